// Round 1
// baseline (3325.113 us; speedup 1.0000x reference)
//
#include <hip/hip_runtime.h>
#include <cstdint>

#define N_NODES 100000
#define E_EDGES 1600000
#define D_IN 64
#define H_DIM 128
#define OUT_DIM 64
#define EPS_GEN 1e-7f
#define BN_EPS 1e-5f
#define NORM_EPS 1e-12f

// ---------------------------------------------------------------------------
// Pass 1 (edges): m = relu(feats[src]+edge_h)+eps; accumulate per (dst,chan):
//   den  += exp(m)        (softmax denominator; max-shift skipped, see note)
//   hnum += m*exp(m)      (softmax-weighted numerator)
// 16 threads/edge, 4 channels each via float4. Single pass over edge_h.
// ---------------------------------------------------------------------------
__global__ __launch_bounds__(256) void edge_pass(
    const float* __restrict__ feats, const float* __restrict__ edge_h,
    const int* __restrict__ src, const int* __restrict__ dst,
    float* __restrict__ den, float* __restrict__ hnum)
{
    int t = blockIdx.x * 256 + threadIdx.x;
    int e = t >> 4;
    if (e >= E_EDGES) return;
    int l = (t & 15) * 4;
    int s = src[e];
    int d = dst[e];
    const float4 xf = *(const float4*)(feats + (size_t)s * D_IN + l);
    const float4 ef = *(const float4*)(edge_h + (size_t)e * D_IN + l);
    float m0 = fmaxf(xf.x + ef.x, 0.f) + EPS_GEN;
    float m1 = fmaxf(xf.y + ef.y, 0.f) + EPS_GEN;
    float m2 = fmaxf(xf.z + ef.z, 0.f) + EPS_GEN;
    float m3 = fmaxf(xf.w + ef.w, 0.f) + EPS_GEN;
    float e0 = __expf(m0), e1 = __expf(m1), e2 = __expf(m2), e3 = __expf(m3);
    float* dp = den  + (size_t)d * D_IN + l;
    float* hp = hnum + (size_t)d * D_IN + l;
    unsafeAtomicAdd(dp + 0, e0);
    unsafeAtomicAdd(dp + 1, e1);
    unsafeAtomicAdd(dp + 2, e2);
    unsafeAtomicAdd(dp + 3, e3);
    unsafeAtomicAdd(hp + 0, m0 * e0);
    unsafeAtomicAdd(hp + 1, m1 * e1);
    unsafeAtomicAdd(hp + 2, m2 * e2);
    unsafeAtomicAdd(hp + 3, m3 * e3);
}

// ---------------------------------------------------------------------------
// Pass 2 (nodes): h = hnum/den; MessageNorm:
//   x = feats + (h/max(||h||,1e-12)) * ||feats|| * scale
// One wave per node, lane = channel; 64-wide shfl-xor reductions for norms.
// NOTE: x aliases den (safe: each thread reads den[idx] before writing x[idx]).
// ---------------------------------------------------------------------------
__global__ __launch_bounds__(256) void node_pass(
    const float* __restrict__ feats, const float* __restrict__ den,
    const float* __restrict__ hnum, const float* __restrict__ scale,
    float* __restrict__ x)
{
    int node = blockIdx.x * 4 + (threadIdx.x >> 6);
    int lane = threadIdx.x & 63;
    if (node >= N_NODES) return;
    size_t idx = (size_t)node * D_IN + lane;
    float dn = den[idx];
    float h  = dn > 0.f ? hnum[idx] / dn : 0.f;
    float f  = feats[idx];
    float s1 = h * h;
    float s2 = f * f;
    #pragma unroll
    for (int off = 32; off > 0; off >>= 1) {
        s1 += __shfl_xor(s1, off, 64);
        s2 += __shfl_xor(s2, off, 64);
    }
    float msgn  = sqrtf(s1);
    float featn = sqrtf(s2);
    float xv = f + (h / fmaxf(msgn, NORM_EPS)) * featn * scale[0];
    x[idx] = xv;
}

// ---------------------------------------------------------------------------
// GEMM1: y1 = x[N,64] @ W1[64,128] + b1, fused BN batch-stat partials.
// Block: 256 thr, tile 32 rows x 128 cols, 4x4 acc/thread. W1 in LDS (32KB).
// ---------------------------------------------------------------------------
__global__ __launch_bounds__(256) void gemm1_stats(
    const float* __restrict__ x, const float* __restrict__ W1,
    const float* __restrict__ b1, float* __restrict__ y1,
    float* __restrict__ stats)
{
    __shared__ float wlds[D_IN * H_DIM];   // 32 KB
    __shared__ float ssum[H_DIM], ssq[H_DIM];
    int tid = threadIdx.x;
    {
        const float4* wg = (const float4*)W1;
        float4* wl = (float4*)wlds;
        #pragma unroll
        for (int i = 0; i < 8; i++) wl[tid + i * 256] = wg[tid + i * 256];
    }
    if (tid < H_DIM) { ssum[tid] = 0.f; ssq[tid] = 0.f; }
    __syncthreads();

    int rg = tid >> 5, cg = tid & 31;
    int r0 = blockIdx.x * 32 + rg * 4;
    int c0 = cg * 4;
    float acc[4][4];
    {
        float4 bb = *(const float4*)(b1 + c0);
        #pragma unroll
        for (int i = 0; i < 4; i++) {
            acc[i][0] = bb.x; acc[i][1] = bb.y; acc[i][2] = bb.z; acc[i][3] = bb.w;
        }
    }
    #pragma unroll 2
    for (int kc = 0; kc < D_IN; kc += 4) {
        float4 xr[4];
        #pragma unroll
        for (int i = 0; i < 4; i++) {
            int r = r0 + i;
            xr[i] = (r < N_NODES) ? *(const float4*)(x + (size_t)r * D_IN + kc)
                                  : make_float4(0.f, 0.f, 0.f, 0.f);
        }
        #pragma unroll
        for (int kk = 0; kk < 4; kk++) {
            float4 w4 = *(const float4*)&wlds[(kc + kk) * H_DIM + c0];
            #pragma unroll
            for (int i = 0; i < 4; i++) {
                float xv = ((const float*)&xr[i])[kk];
                acc[i][0] = fmaf(xv, w4.x, acc[i][0]);
                acc[i][1] = fmaf(xv, w4.y, acc[i][1]);
                acc[i][2] = fmaf(xv, w4.z, acc[i][2]);
                acc[i][3] = fmaf(xv, w4.w, acc[i][3]);
            }
        }
    }
    float cs[4] = {0.f, 0.f, 0.f, 0.f}, cq[4] = {0.f, 0.f, 0.f, 0.f};
    #pragma unroll
    for (int i = 0; i < 4; i++) {
        int r = r0 + i;
        if (r < N_NODES) {
            *(float4*)(y1 + (size_t)r * H_DIM + c0) =
                make_float4(acc[i][0], acc[i][1], acc[i][2], acc[i][3]);
            #pragma unroll
            for (int j = 0; j < 4; j++) {
                cs[j] += acc[i][j];
                cq[j] += acc[i][j] * acc[i][j];
            }
        }
    }
    #pragma unroll
    for (int j = 0; j < 4; j++) {
        atomicAdd(&ssum[c0 + j], cs[j]);
        atomicAdd(&ssq[c0 + j], cq[j]);
    }
    __syncthreads();
    if (tid < H_DIM) {
        unsafeAtomicAdd(&stats[tid], ssum[tid]);
        unsafeAtomicAdd(&stats[H_DIM + tid], ssq[tid]);
    }
}

// ---------------------------------------------------------------------------
// BN prep: per-channel scale/shift from batch stats (biased var, torch BN).
// ---------------------------------------------------------------------------
__global__ void bn_prep(const float* __restrict__ stats,
                        const float* __restrict__ gamma,
                        const float* __restrict__ beta,
                        float* __restrict__ ssb)
{
    int c = threadIdx.x;
    if (c < H_DIM) {
        float mean = stats[c] * (1.f / N_NODES);
        float var  = stats[H_DIM + c] * (1.f / N_NODES) - mean * mean;
        float rs   = rsqrtf(var + BN_EPS);
        float sc   = gamma[c] * rs;
        ssb[c]         = sc;
        ssb[H_DIM + c] = beta[c] - mean * sc;
    }
}

// ---------------------------------------------------------------------------
// GEMM2: out = relu(BN(y1)) @ W2 + b2. BN+ReLU fused into the A-load.
// Block: 256 thr, tile 64 rows x 64 cols, 4x4 acc/thread. W2 in LDS (32KB).
// ---------------------------------------------------------------------------
__global__ __launch_bounds__(256) void gemm2_bn(
    const float* __restrict__ y1, const float* __restrict__ W2,
    const float* __restrict__ b2, const float* __restrict__ ssb,
    float* __restrict__ out)
{
    __shared__ float wlds[H_DIM * OUT_DIM];   // 32 KB
    __shared__ float sc[H_DIM], sh[H_DIM];
    int tid = threadIdx.x;
    {
        const float4* wg = (const float4*)W2;
        float4* wl = (float4*)wlds;
        #pragma unroll
        for (int i = 0; i < 8; i++) wl[tid + i * 256] = wg[tid + i * 256];
    }
    if (tid < H_DIM) { sc[tid] = ssb[tid]; sh[tid] = ssb[H_DIM + tid]; }
    __syncthreads();

    int rg = tid >> 4, cg = tid & 15;
    int r0 = blockIdx.x * 64 + rg * 4;
    int c0 = cg * 4;
    float acc[4][4];
    {
        float4 bb = *(const float4*)(b2 + c0);
        #pragma unroll
        for (int i = 0; i < 4; i++) {
            acc[i][0] = bb.x; acc[i][1] = bb.y; acc[i][2] = bb.z; acc[i][3] = bb.w;
        }
    }
    #pragma unroll 2
    for (int kc = 0; kc < H_DIM; kc += 4) {
        float4 sc4 = *(const float4*)&sc[kc];
        float4 sh4 = *(const float4*)&sh[kc];
        float4 yr[4];
        #pragma unroll
        for (int i = 0; i < 4; i++) {
            int r = r0 + i;
            if (r < N_NODES) {
                float4 v = *(const float4*)(y1 + (size_t)r * H_DIM + kc);
                v.x = fmaxf(fmaf(v.x, sc4.x, sh4.x), 0.f);
                v.y = fmaxf(fmaf(v.y, sc4.y, sh4.y), 0.f);
                v.z = fmaxf(fmaf(v.z, sc4.z, sh4.z), 0.f);
                v.w = fmaxf(fmaf(v.w, sc4.w, sh4.w), 0.f);
                yr[i] = v;
            } else {
                yr[i] = make_float4(0.f, 0.f, 0.f, 0.f);
            }
        }
        #pragma unroll
        for (int kk = 0; kk < 4; kk++) {
            float4 w4 = *(const float4*)&wlds[(kc + kk) * OUT_DIM + c0];
            #pragma unroll
            for (int i = 0; i < 4; i++) {
                float yv = ((const float*)&yr[i])[kk];
                acc[i][0] = fmaf(yv, w4.x, acc[i][0]);
                acc[i][1] = fmaf(yv, w4.y, acc[i][1]);
                acc[i][2] = fmaf(yv, w4.z, acc[i][2]);
                acc[i][3] = fmaf(yv, w4.w, acc[i][3]);
            }
        }
    }
    #pragma unroll
    for (int i = 0; i < 4; i++) {
        int r = r0 + i;
        if (r < N_NODES) {
            *(float4*)(out + (size_t)r * OUT_DIM + c0) =
                make_float4(acc[i][0], acc[i][1], acc[i][2], acc[i][3]);
        }
    }
}

// ---------------------------------------------------------------------------
// Workspace layout (floats):
//   [0, ND)            den   (aliased as x after node_pass)
//   [ND, 2ND)          hnum
//   [2ND, 2ND+256)     stats (sum[128], sumsq[128])  -- zeroed
//   [2ND+256, 2ND+512) ssb   (scale[128], shift[128])
//   [2ND+512, ...)     y1    (N x 128)
// Total: 2*6.4M + 512 + 12.8M floats ~= 102.4 MB
// ---------------------------------------------------------------------------
extern "C" void kernel_launch(void* const* d_in, const int* in_sizes, int n_in,
                              void* d_out, int out_size, void* d_ws, size_t ws_size,
                              hipStream_t stream)
{
    const float* feats   = (const float*)d_in[0];
    const float* edge_h  = (const float*)d_in[1];
    const int*   src     = (const int*)d_in[2];
    const int*   dst     = (const int*)d_in[3];
    const float* W1      = (const float*)d_in[4];
    const float* b1      = (const float*)d_in[5];
    const float* gamma   = (const float*)d_in[6];
    const float* bn_beta = (const float*)d_in[7];
    const float* W2      = (const float*)d_in[8];
    const float* b2      = (const float*)d_in[9];
    const float* scale   = (const float*)d_in[10];
    float* out = (float*)d_out;

    const size_t ND = (size_t)N_NODES * D_IN;   // 6.4M
    float* ws    = (float*)d_ws;
    float* den   = ws;
    float* hnum  = den + ND;
    float* stats = hnum + ND;
    float* ssb   = stats + 256;
    float* xbuf  = den;            // alias: x overwrites den in node_pass
    float* y1    = ssb + 256;

    // zero den + hnum + stats in one contiguous memset
    hipMemsetAsync(den, 0, (2 * ND + 256) * sizeof(float), stream);

    edge_pass<<<(E_EDGES * 16) / 256, 256, 0, stream>>>(feats, edge_h, src, dst, den, hnum);
    node_pass<<<(N_NODES + 3) / 4, 256, 0, stream>>>(feats, den, hnum, scale, xbuf);
    gemm1_stats<<<(N_NODES + 31) / 32, 256, 0, stream>>>(xbuf, W1, b1, y1, stats);
    bn_prep<<<1, 128, 0, stream>>>(stats, gamma, bn_beta, ssb);
    gemm2_bn<<<(N_NODES + 63) / 64, 256, 0, stream>>>(y1, W2, b2, ssb, out);
}

// Round 2
// 1072.103 us; speedup vs baseline: 3.1015x; 3.1015x over previous
//
#include <hip/hip_runtime.h>
#include <cstdint>

#define N_NODES 100000
#define E_EDGES 1600000
#define D_IN 64
#define H_DIM 128
#define OUT_DIM 64
#define EPS_GEN 1e-7f
#define BN_EPS 1e-5f
#define NORM_EPS 1e-12f

// ---------------------------------------------------------------------------
// CSR build, step 1: per-dst degree histogram. 1.6M int atomics over 400 KB.
// ---------------------------------------------------------------------------
__global__ __launch_bounds__(256) void hist_kernel(
    const int* __restrict__ dst, int* __restrict__ counts)
{
    int t = blockIdx.x * 256 + threadIdx.x;
    if (t < E_EDGES) atomicAdd(&counts[dst[t]], 1);
}

// ---------------------------------------------------------------------------
// CSR build, step 2a: per-block inclusive scan of counts (256/block).
// Inclusive result goes into row_start (temporarily), block totals to bsum.
// ---------------------------------------------------------------------------
__global__ __launch_bounds__(256) void scan1(
    const int* __restrict__ counts, int* __restrict__ row_start,
    int* __restrict__ bsum)
{
    __shared__ int s[256];
    int t = threadIdx.x, g = blockIdx.x * 256 + t;
    int v = (g < N_NODES) ? counts[g] : 0;
    s[t] = v;
    __syncthreads();
    #pragma unroll
    for (int off = 1; off < 256; off <<= 1) {
        int u = (t >= off) ? s[t - off] : 0;
        __syncthreads();
        s[t] += u;
        __syncthreads();
    }
    if (g < N_NODES) row_start[g] = s[t];
    if (t == 255) bsum[blockIdx.x] = s[255];
}

// ---------------------------------------------------------------------------
// CSR build, step 2b: exclusive scan of the 391 block sums (single block).
// ---------------------------------------------------------------------------
__global__ __launch_bounds__(512) void scan2(int* __restrict__ bsum, int nb)
{
    __shared__ int s[512];
    int t = threadIdx.x;
    int v = (t < nb) ? bsum[t] : 0;
    s[t] = v;
    __syncthreads();
    #pragma unroll
    for (int off = 1; off < 512; off <<= 1) {
        int u = (t >= off) ? s[t - off] : 0;
        __syncthreads();
        s[t] += u;
        __syncthreads();
    }
    if (t < nb) bsum[t] = s[t] - v;   // exclusive
}

// ---------------------------------------------------------------------------
// CSR build, step 2c: combine into global exclusive row_start; init cursors.
// ---------------------------------------------------------------------------
__global__ __launch_bounds__(256) void scan3(
    const int* __restrict__ counts, const int* __restrict__ bsum,
    int* __restrict__ row_start, int* __restrict__ next)
{
    int g = blockIdx.x * 256 + threadIdx.x;
    if (g < N_NODES) {
        int incl = row_start[g];                   // from scan1
        int rs = incl - counts[g] + bsum[blockIdx.x];
        row_start[g] = rs;
        next[g] = rs;
    }
    if (g == 0) row_start[N_NODES] = E_EDGES;
}

// ---------------------------------------------------------------------------
// CSR build, step 3: scatter edge ids into dst-sorted order.
// ---------------------------------------------------------------------------
__global__ __launch_bounds__(256) void scatter_k(
    const int* __restrict__ dst, int* __restrict__ next, int* __restrict__ eid)
{
    int t = blockIdx.x * 256 + threadIdx.x;
    if (t < E_EDGES) {
        int p = atomicAdd(&next[dst[t]], 1);
        eid[p] = t;
    }
}

// ---------------------------------------------------------------------------
// Fused aggregation + MessageNorm. One wave per node, lane = channel.
//   den = sum exp(m), hn = sum m*exp(m)  (softmax max-shift cancels, values
//   bounded ~[0,10] so exp is safe in f32)
//   h = hn/den; x = feats + (h/max(||h||,eps)) * ||feats|| * scale
// Zero f32 atomics. Unrolled by 2 to overlap the eid->src->feats load chain.
// ---------------------------------------------------------------------------
__global__ __launch_bounds__(256) void aggregate(
    const float* __restrict__ feats, const float* __restrict__ edge_h,
    const int* __restrict__ srcA, const int* __restrict__ row_start,
    const int* __restrict__ eid, const float* __restrict__ scale,
    float* __restrict__ x)
{
    int node = blockIdx.x * 4 + (threadIdx.x >> 6);
    int lane = threadIdx.x & 63;
    if (node >= N_NODES) return;
    int rs = row_start[node], re = row_start[node + 1];
    float den = 0.f, hn = 0.f;
    int i = rs;
    for (; i + 2 <= re; i += 2) {
        int ea = eid[i], eb = eid[i + 1];
        int sa = srcA[ea], sb = srcA[eb];
        float fa = feats[(size_t)sa * D_IN + lane];
        float fb = feats[(size_t)sb * D_IN + lane];
        float va = edge_h[(size_t)ea * D_IN + lane];
        float vb = edge_h[(size_t)eb * D_IN + lane];
        float ma = fmaxf(fa + va, 0.f) + EPS_GEN;
        float mb = fmaxf(fb + vb, 0.f) + EPS_GEN;
        float xa = __expf(ma), xb = __expf(mb);
        den += xa + xb;
        hn = fmaf(ma, xa, hn);
        hn = fmaf(mb, xb, hn);
    }
    if (i < re) {
        int ea = eid[i];
        int sa = srcA[ea];
        float fa = feats[(size_t)sa * D_IN + lane];
        float va = edge_h[(size_t)ea * D_IN + lane];
        float ma = fmaxf(fa + va, 0.f) + EPS_GEN;
        float xa = __expf(ma);
        den += xa;
        hn = fmaf(ma, xa, hn);
    }
    float h = den > 0.f ? hn / den : 0.f;
    float f = feats[(size_t)node * D_IN + lane];
    float s1 = h * h, s2 = f * f;
    #pragma unroll
    for (int off = 32; off > 0; off >>= 1) {
        s1 += __shfl_xor(s1, off, 64);
        s2 += __shfl_xor(s2, off, 64);
    }
    float xv = f + (h / fmaxf(sqrtf(s1), NORM_EPS)) * sqrtf(s2) * scale[0];
    x[(size_t)node * D_IN + lane] = xv;
}

// ---------------------------------------------------------------------------
// GEMM1: y1 = x[N,64] @ W1[64,128] + b1, fused BN batch-stat partials.
// Block: 256 thr, tile 32 rows x 128 cols, 4x4 acc/thread. W1 in LDS (32KB).
// ---------------------------------------------------------------------------
__global__ __launch_bounds__(256) void gemm1_stats(
    const float* __restrict__ x, const float* __restrict__ W1,
    const float* __restrict__ b1, float* __restrict__ y1,
    float* __restrict__ stats)
{
    __shared__ float wlds[D_IN * H_DIM];   // 32 KB
    __shared__ float ssum[H_DIM], ssq[H_DIM];
    int tid = threadIdx.x;
    {
        const float4* wg = (const float4*)W1;
        float4* wl = (float4*)wlds;
        #pragma unroll
        for (int i = 0; i < 8; i++) wl[tid + i * 256] = wg[tid + i * 256];
    }
    if (tid < H_DIM) { ssum[tid] = 0.f; ssq[tid] = 0.f; }
    __syncthreads();

    int rg = tid >> 5, cg = tid & 31;
    int r0 = blockIdx.x * 32 + rg * 4;
    int c0 = cg * 4;
    float acc[4][4];
    {
        float4 bb = *(const float4*)(b1 + c0);
        #pragma unroll
        for (int i = 0; i < 4; i++) {
            acc[i][0] = bb.x; acc[i][1] = bb.y; acc[i][2] = bb.z; acc[i][3] = bb.w;
        }
    }
    #pragma unroll 2
    for (int kc = 0; kc < D_IN; kc += 4) {
        float4 xr[4];
        #pragma unroll
        for (int i = 0; i < 4; i++) {
            int r = r0 + i;
            xr[i] = (r < N_NODES) ? *(const float4*)(x + (size_t)r * D_IN + kc)
                                  : make_float4(0.f, 0.f, 0.f, 0.f);
        }
        #pragma unroll
        for (int kk = 0; kk < 4; kk++) {
            float4 w4 = *(const float4*)&wlds[(kc + kk) * H_DIM + c0];
            #pragma unroll
            for (int i = 0; i < 4; i++) {
                float xv = ((const float*)&xr[i])[kk];
                acc[i][0] = fmaf(xv, w4.x, acc[i][0]);
                acc[i][1] = fmaf(xv, w4.y, acc[i][1]);
                acc[i][2] = fmaf(xv, w4.z, acc[i][2]);
                acc[i][3] = fmaf(xv, w4.w, acc[i][3]);
            }
        }
    }
    float cs[4] = {0.f, 0.f, 0.f, 0.f}, cq[4] = {0.f, 0.f, 0.f, 0.f};
    #pragma unroll
    for (int i = 0; i < 4; i++) {
        int r = r0 + i;
        if (r < N_NODES) {
            *(float4*)(y1 + (size_t)r * H_DIM + c0) =
                make_float4(acc[i][0], acc[i][1], acc[i][2], acc[i][3]);
            #pragma unroll
            for (int j = 0; j < 4; j++) {
                cs[j] += acc[i][j];
                cq[j] += acc[i][j] * acc[i][j];
            }
        }
    }
    #pragma unroll
    for (int j = 0; j < 4; j++) {
        atomicAdd(&ssum[c0 + j], cs[j]);
        atomicAdd(&ssq[c0 + j], cq[j]);
    }
    __syncthreads();
    if (tid < H_DIM) {
        unsafeAtomicAdd(&stats[tid], ssum[tid]);
        unsafeAtomicAdd(&stats[H_DIM + tid], ssq[tid]);
    }
}

// ---------------------------------------------------------------------------
// BN prep: per-channel scale/shift from batch stats (biased var, torch BN).
// ---------------------------------------------------------------------------
__global__ void bn_prep(const float* __restrict__ stats,
                        const float* __restrict__ gamma,
                        const float* __restrict__ beta,
                        float* __restrict__ ssb)
{
    int c = threadIdx.x;
    if (c < H_DIM) {
        float mean = stats[c] * (1.f / N_NODES);
        float var  = stats[H_DIM + c] * (1.f / N_NODES) - mean * mean;
        float rs   = rsqrtf(var + BN_EPS);
        float sc   = gamma[c] * rs;
        ssb[c]         = sc;
        ssb[H_DIM + c] = beta[c] - mean * sc;
    }
}

// ---------------------------------------------------------------------------
// GEMM2: out = relu(BN(y1)) @ W2 + b2. BN+ReLU fused into the A-load.
// Block: 256 thr, tile 64 rows x 64 cols, 4x4 acc/thread. W2 in LDS (32KB).
// ---------------------------------------------------------------------------
__global__ __launch_bounds__(256) void gemm2_bn(
    const float* __restrict__ y1, const float* __restrict__ W2,
    const float* __restrict__ b2, const float* __restrict__ ssb,
    float* __restrict__ out)
{
    __shared__ float wlds[H_DIM * OUT_DIM];   // 32 KB
    __shared__ float sc[H_DIM], sh[H_DIM];
    int tid = threadIdx.x;
    {
        const float4* wg = (const float4*)W2;
        float4* wl = (float4*)wlds;
        #pragma unroll
        for (int i = 0; i < 8; i++) wl[tid + i * 256] = wg[tid + i * 256];
    }
    if (tid < H_DIM) { sc[tid] = ssb[tid]; sh[tid] = ssb[H_DIM + tid]; }
    __syncthreads();

    int rg = tid >> 4, cg = tid & 15;
    int r0 = blockIdx.x * 64 + rg * 4;
    int c0 = cg * 4;
    float acc[4][4];
    {
        float4 bb = *(const float4*)(b2 + c0);
        #pragma unroll
        for (int i = 0; i < 4; i++) {
            acc[i][0] = bb.x; acc[i][1] = bb.y; acc[i][2] = bb.z; acc[i][3] = bb.w;
        }
    }
    #pragma unroll 2
    for (int kc = 0; kc < H_DIM; kc += 4) {
        float4 sc4 = *(const float4*)&sc[kc];
        float4 sh4 = *(const float4*)&sh[kc];
        float4 yr[4];
        #pragma unroll
        for (int i = 0; i < 4; i++) {
            int r = r0 + i;
            if (r < N_NODES) {
                float4 v = *(const float4*)(y1 + (size_t)r * H_DIM + kc);
                v.x = fmaxf(fmaf(v.x, sc4.x, sh4.x), 0.f);
                v.y = fmaxf(fmaf(v.y, sc4.y, sh4.y), 0.f);
                v.z = fmaxf(fmaf(v.z, sc4.z, sh4.z), 0.f);
                v.w = fmaxf(fmaf(v.w, sc4.w, sh4.w), 0.f);
                yr[i] = v;
            } else {
                yr[i] = make_float4(0.f, 0.f, 0.f, 0.f);
            }
        }
        #pragma unroll
        for (int kk = 0; kk < 4; kk++) {
            float4 w4 = *(const float4*)&wlds[(kc + kk) * OUT_DIM + c0];
            #pragma unroll
            for (int i = 0; i < 4; i++) {
                float yv = ((const float*)&yr[i])[kk];
                acc[i][0] = fmaf(yv, w4.x, acc[i][0]);
                acc[i][1] = fmaf(yv, w4.y, acc[i][1]);
                acc[i][2] = fmaf(yv, w4.z, acc[i][2]);
                acc[i][3] = fmaf(yv, w4.w, acc[i][3]);
            }
        }
    }
    #pragma unroll
    for (int i = 0; i < 4; i++) {
        int r = r0 + i;
        if (r < N_NODES) {
            *(float4*)(out + (size_t)r * OUT_DIM + c0) =
                make_float4(acc[i][0], acc[i][1], acc[i][2], acc[i][3]);
        }
    }
}

// ---------------------------------------------------------------------------
// Workspace layout (4-byte elements):
//   counts    int[N]          \ zeroed together (N + 256 elements)
//   stats     float[256]      /
//   bsum      int[512]
//   row_start int[N+1]
//   next      int[N]
//   eid       int[E]
//   x         float[N*64]
//   y1        float[N*128]
//   ssb       float[256]
// Total ~84.5 MB.
// ---------------------------------------------------------------------------
extern "C" void kernel_launch(void* const* d_in, const int* in_sizes, int n_in,
                              void* d_out, int out_size, void* d_ws, size_t ws_size,
                              hipStream_t stream)
{
    const float* feats   = (const float*)d_in[0];
    const float* edge_h  = (const float*)d_in[1];
    const int*   src     = (const int*)d_in[2];
    const int*   dst     = (const int*)d_in[3];
    const float* W1      = (const float*)d_in[4];
    const float* b1      = (const float*)d_in[5];
    const float* gamma   = (const float*)d_in[6];
    const float* bn_beta = (const float*)d_in[7];
    const float* W2      = (const float*)d_in[8];
    const float* b2      = (const float*)d_in[9];
    const float* scale   = (const float*)d_in[10];
    float* out = (float*)d_out;

    const size_t ND = (size_t)N_NODES * D_IN;
    char* ws = (char*)d_ws;
    int*   counts    = (int*)ws;                          ws += (size_t)N_NODES * 4;
    float* stats     = (float*)ws;                        ws += 256 * 4;
    int*   bsum      = (int*)ws;                          ws += 512 * 4;
    int*   row_start = (int*)ws;                          ws += (size_t)(N_NODES + 1) * 4;
    int*   next      = (int*)ws;                          ws += (size_t)N_NODES * 4;
    int*   eid       = (int*)ws;                          ws += (size_t)E_EDGES * 4;
    float* xbuf      = (float*)ws;                        ws += ND * 4;
    float* y1        = (float*)ws;                        ws += (size_t)N_NODES * H_DIM * 4;
    float* ssb       = (float*)ws;

    const int NB = (N_NODES + 255) / 256;   // 391

    // zero counts + stats in one memset (contiguous)
    hipMemsetAsync(counts, 0, (size_t)(N_NODES + 256) * 4, stream);

    hist_kernel<<<(E_EDGES + 255) / 256, 256, 0, stream>>>(dst, counts);
    scan1<<<NB, 256, 0, stream>>>(counts, row_start, bsum);
    scan2<<<1, 512, 0, stream>>>(bsum, NB);
    scan3<<<NB, 256, 0, stream>>>(counts, bsum, row_start, next);
    scatter_k<<<(E_EDGES + 255) / 256, 256, 0, stream>>>(dst, next, eid);
    aggregate<<<(N_NODES + 3) / 4, 256, 0, stream>>>(feats, edge_h, src, row_start, eid, scale, xbuf);
    gemm1_stats<<<(N_NODES + 31) / 32, 256, 0, stream>>>(xbuf, W1, b1, y1, stats);
    bn_prep<<<1, 128, 0, stream>>>(stats, gamma, bn_beta, ssb);
    gemm2_bn<<<(N_NODES + 63) / 64, 256, 0, stream>>>(y1, W2, b2, ssb, out);
}

// Round 3
// 971.448 us; speedup vs baseline: 3.4228x; 1.1036x over previous
//
#include <hip/hip_runtime.h>
#include <cstdint>

#define N_NODES 100000
#define E_EDGES 1600000
#define D_IN 64
#define H_DIM 128
#define OUT_DIM 64
#define EPS_GEN 1e-7f
#define BN_EPS 1e-5f
#define NORM_EPS 1e-12f

// ---------------------------------------------------------------------------
// CSR build, step 1: per-dst degree histogram.
// ---------------------------------------------------------------------------
__global__ __launch_bounds__(256) void hist_kernel(
    const int* __restrict__ dst, int* __restrict__ counts)
{
    int t = blockIdx.x * 256 + threadIdx.x;
    if (t < E_EDGES) atomicAdd(&counts[dst[t]], 1);
}

// ---------------------------------------------------------------------------
// CSR build, step 2a: per-block inclusive scan of counts (256/block).
// ---------------------------------------------------------------------------
__global__ __launch_bounds__(256) void scan1(
    const int* __restrict__ counts, int* __restrict__ row_start,
    int* __restrict__ bsum)
{
    __shared__ int s[256];
    int t = threadIdx.x, g = blockIdx.x * 256 + t;
    int v = (g < N_NODES) ? counts[g] : 0;
    s[t] = v;
    __syncthreads();
    #pragma unroll
    for (int off = 1; off < 256; off <<= 1) {
        int u = (t >= off) ? s[t - off] : 0;
        __syncthreads();
        s[t] += u;
        __syncthreads();
    }
    if (g < N_NODES) row_start[g] = s[t];
    if (t == 255) bsum[blockIdx.x] = s[255];
}

// ---------------------------------------------------------------------------
// CSR build, step 2b: exclusive scan of the 391 block sums (single block).
// ---------------------------------------------------------------------------
__global__ __launch_bounds__(512) void scan2(int* __restrict__ bsum, int nb)
{
    __shared__ int s[512];
    int t = threadIdx.x;
    int v = (t < nb) ? bsum[t] : 0;
    s[t] = v;
    __syncthreads();
    #pragma unroll
    for (int off = 1; off < 512; off <<= 1) {
        int u = (t >= off) ? s[t - off] : 0;
        __syncthreads();
        s[t] += u;
        __syncthreads();
    }
    if (t < nb) bsum[t] = s[t] - v;   // exclusive
}

// ---------------------------------------------------------------------------
// CSR build, step 2c: combine into global exclusive row_start; init cursors.
// ---------------------------------------------------------------------------
__global__ __launch_bounds__(256) void scan3(
    const int* __restrict__ counts, const int* __restrict__ bsum,
    int* __restrict__ row_start, int* __restrict__ next)
{
    int g = blockIdx.x * 256 + threadIdx.x;
    if (g < N_NODES) {
        int incl = row_start[g];                   // from scan1
        int rs = incl - counts[g] + bsum[blockIdx.x];
        row_start[g] = rs;
        next[g] = rs;
    }
    if (g == 0) row_start[N_NODES] = E_EDGES;
}

// ---------------------------------------------------------------------------
// CSR build, step 3: scatter {edge id, src id} into dst-sorted adjacency.
// Resolving src here (coalesced read) removes one level of the dependent
// load chain from the aggregate kernel.
// ---------------------------------------------------------------------------
__global__ __launch_bounds__(256) void scatter_k(
    const int* __restrict__ dst, const int* __restrict__ src,
    int* __restrict__ next, int2* __restrict__ adj)
{
    int t = blockIdx.x * 256 + threadIdx.x;
    if (t < E_EDGES) {
        int p = atomicAdd(&next[dst[t]], 1);
        adj[p] = make_int2(t, src[t]);
    }
}

// ---------------------------------------------------------------------------
// Fused aggregation + MessageNorm. One wave per node, lane = channel.
// Adjacency for the node is loaded COALESCED (lane-parallel, 64 entries per
// chunk) then broadcast per-edge via __shfl — no per-edge pointer chasing.
// Inner loop unrolled x4: 8 independent 256B row loads in flight per wave.
//   den = sum exp(m), hn = sum m*exp(m)  (softmax max-shift cancels; m is
//   bounded ~[1e-7,10] so exp is safe in f32)
//   h = hn/den; x = feats + (h/max(||h||,eps)) * ||feats|| * scale
// ---------------------------------------------------------------------------
__global__ __launch_bounds__(256) void aggregate(
    const float* __restrict__ feats, const float* __restrict__ edge_h,
    const int2* __restrict__ adj, const int* __restrict__ row_start,
    const float* __restrict__ scale, float* __restrict__ x)
{
    int node = blockIdx.x * 4 + (threadIdx.x >> 6);
    int lane = threadIdx.x & 63;
    if (node >= N_NODES) return;
    int rs = row_start[node], re = row_start[node + 1];
    float den = 0.f, hn = 0.f;

    for (int base = rs; base < re; base += 64) {
        int cnt = min(64, re - base);
        int2 ad = (base + lane < re) ? adj[base + lane] : make_int2(0, 0);
        int j = 0;
        for (; j + 4 <= cnt; j += 4) {
            int e0 = __shfl(ad.x, j),     s0 = __shfl(ad.y, j);
            int e1 = __shfl(ad.x, j + 1), s1 = __shfl(ad.y, j + 1);
            int e2 = __shfl(ad.x, j + 2), s2 = __shfl(ad.y, j + 2);
            int e3 = __shfl(ad.x, j + 3), s3 = __shfl(ad.y, j + 3);
            float f0 = feats[(size_t)s0 * D_IN + lane];
            float v0 = edge_h[(size_t)e0 * D_IN + lane];
            float f1 = feats[(size_t)s1 * D_IN + lane];
            float v1 = edge_h[(size_t)e1 * D_IN + lane];
            float f2 = feats[(size_t)s2 * D_IN + lane];
            float v2 = edge_h[(size_t)e2 * D_IN + lane];
            float f3 = feats[(size_t)s3 * D_IN + lane];
            float v3 = edge_h[(size_t)e3 * D_IN + lane];
            float m0 = fmaxf(f0 + v0, 0.f) + EPS_GEN;
            float m1 = fmaxf(f1 + v1, 0.f) + EPS_GEN;
            float m2 = fmaxf(f2 + v2, 0.f) + EPS_GEN;
            float m3 = fmaxf(f3 + v3, 0.f) + EPS_GEN;
            float x0 = __expf(m0), x1 = __expf(m1);
            float x2 = __expf(m2), x3 = __expf(m3);
            den += (x0 + x1) + (x2 + x3);
            hn = fmaf(m0, x0, hn);
            hn = fmaf(m1, x1, hn);
            hn = fmaf(m2, x2, hn);
            hn = fmaf(m3, x3, hn);
        }
        for (; j < cnt; j++) {
            int e0 = __shfl(ad.x, j), s0 = __shfl(ad.y, j);
            float f0 = feats[(size_t)s0 * D_IN + lane];
            float v0 = edge_h[(size_t)e0 * D_IN + lane];
            float m0 = fmaxf(f0 + v0, 0.f) + EPS_GEN;
            float x0 = __expf(m0);
            den += x0;
            hn = fmaf(m0, x0, hn);
        }
    }

    float h = den > 0.f ? hn / den : 0.f;
    float f = feats[(size_t)node * D_IN + lane];
    float s1 = h * h, s2 = f * f;
    #pragma unroll
    for (int off = 32; off > 0; off >>= 1) {
        s1 += __shfl_xor(s1, off, 64);
        s2 += __shfl_xor(s2, off, 64);
    }
    float xv = f + (h / fmaxf(sqrtf(s1), NORM_EPS)) * sqrtf(s2) * scale[0];
    x[(size_t)node * D_IN + lane] = xv;
}

// ---------------------------------------------------------------------------
// GEMM1: y1 = x[N,64] @ W1[64,128] + b1, fused BN batch-stat partials.
// Block: 256 thr, tile 32 rows x 128 cols, 4x4 acc/thread. W1 in LDS (32KB).
// ---------------------------------------------------------------------------
__global__ __launch_bounds__(256) void gemm1_stats(
    const float* __restrict__ x, const float* __restrict__ W1,
    const float* __restrict__ b1, float* __restrict__ y1,
    float* __restrict__ stats)
{
    __shared__ float wlds[D_IN * H_DIM];   // 32 KB
    __shared__ float ssum[H_DIM], ssq[H_DIM];
    int tid = threadIdx.x;
    {
        const float4* wg = (const float4*)W1;
        float4* wl = (float4*)wlds;
        #pragma unroll
        for (int i = 0; i < 8; i++) wl[tid + i * 256] = wg[tid + i * 256];
    }
    if (tid < H_DIM) { ssum[tid] = 0.f; ssq[tid] = 0.f; }
    __syncthreads();

    int rg = tid >> 5, cg = tid & 31;
    int r0 = blockIdx.x * 32 + rg * 4;
    int c0 = cg * 4;
    float acc[4][4];
    {
        float4 bb = *(const float4*)(b1 + c0);
        #pragma unroll
        for (int i = 0; i < 4; i++) {
            acc[i][0] = bb.x; acc[i][1] = bb.y; acc[i][2] = bb.z; acc[i][3] = bb.w;
        }
    }
    #pragma unroll 2
    for (int kc = 0; kc < D_IN; kc += 4) {
        float4 xr[4];
        #pragma unroll
        for (int i = 0; i < 4; i++) {
            int r = r0 + i;
            xr[i] = (r < N_NODES) ? *(const float4*)(x + (size_t)r * D_IN + kc)
                                  : make_float4(0.f, 0.f, 0.f, 0.f);
        }
        #pragma unroll
        for (int kk = 0; kk < 4; kk++) {
            float4 w4 = *(const float4*)&wlds[(kc + kk) * H_DIM + c0];
            #pragma unroll
            for (int i = 0; i < 4; i++) {
                float xv = ((const float*)&xr[i])[kk];
                acc[i][0] = fmaf(xv, w4.x, acc[i][0]);
                acc[i][1] = fmaf(xv, w4.y, acc[i][1]);
                acc[i][2] = fmaf(xv, w4.z, acc[i][2]);
                acc[i][3] = fmaf(xv, w4.w, acc[i][3]);
            }
        }
    }
    float cs[4] = {0.f, 0.f, 0.f, 0.f}, cq[4] = {0.f, 0.f, 0.f, 0.f};
    #pragma unroll
    for (int i = 0; i < 4; i++) {
        int r = r0 + i;
        if (r < N_NODES) {
            *(float4*)(y1 + (size_t)r * H_DIM + c0) =
                make_float4(acc[i][0], acc[i][1], acc[i][2], acc[i][3]);
            #pragma unroll
            for (int j = 0; j < 4; j++) {
                cs[j] += acc[i][j];
                cq[j] += acc[i][j] * acc[i][j];
            }
        }
    }
    #pragma unroll
    for (int j = 0; j < 4; j++) {
        atomicAdd(&ssum[c0 + j], cs[j]);
        atomicAdd(&ssq[c0 + j], cq[j]);
    }
    __syncthreads();
    if (tid < H_DIM) {
        unsafeAtomicAdd(&stats[tid], ssum[tid]);
        unsafeAtomicAdd(&stats[H_DIM + tid], ssq[tid]);
    }
}

// ---------------------------------------------------------------------------
// GEMM2: out = relu(BN(y1)) @ W2 + b2. BN scale/shift computed per-block
// from batch stats (bn_prep folded in); BN+ReLU fused into the A-load.
// Block: 256 thr, tile 64 rows x 64 cols, 4x4 acc/thread. W2 in LDS (32KB).
// ---------------------------------------------------------------------------
__global__ __launch_bounds__(256) void gemm2_bn(
    const float* __restrict__ y1, const float* __restrict__ W2,
    const float* __restrict__ b2, const float* __restrict__ stats,
    const float* __restrict__ gamma, const float* __restrict__ beta,
    float* __restrict__ out)
{
    __shared__ float wlds[H_DIM * OUT_DIM];   // 32 KB
    __shared__ float sc[H_DIM], sh[H_DIM];
    int tid = threadIdx.x;
    {
        const float4* wg = (const float4*)W2;
        float4* wl = (float4*)wlds;
        #pragma unroll
        for (int i = 0; i < 8; i++) wl[tid + i * 256] = wg[tid + i * 256];
    }
    if (tid < H_DIM) {
        float mean = stats[tid] * (1.f / N_NODES);
        float var  = stats[H_DIM + tid] * (1.f / N_NODES) - mean * mean;
        float rs   = rsqrtf(var + BN_EPS);
        float s    = gamma[tid] * rs;
        sc[tid] = s;
        sh[tid] = beta[tid] - mean * s;
    }
    __syncthreads();

    int rg = tid >> 4, cg = tid & 15;
    int r0 = blockIdx.x * 64 + rg * 4;
    int c0 = cg * 4;
    float acc[4][4];
    {
        float4 bb = *(const float4*)(b2 + c0);
        #pragma unroll
        for (int i = 0; i < 4; i++) {
            acc[i][0] = bb.x; acc[i][1] = bb.y; acc[i][2] = bb.z; acc[i][3] = bb.w;
        }
    }
    #pragma unroll 2
    for (int kc = 0; kc < H_DIM; kc += 4) {
        float4 sc4 = *(const float4*)&sc[kc];
        float4 sh4 = *(const float4*)&sh[kc];
        float4 yr[4];
        #pragma unroll
        for (int i = 0; i < 4; i++) {
            int r = r0 + i;
            if (r < N_NODES) {
                float4 v = *(const float4*)(y1 + (size_t)r * H_DIM + kc);
                v.x = fmaxf(fmaf(v.x, sc4.x, sh4.x), 0.f);
                v.y = fmaxf(fmaf(v.y, sc4.y, sh4.y), 0.f);
                v.z = fmaxf(fmaf(v.z, sc4.z, sh4.z), 0.f);
                v.w = fmaxf(fmaf(v.w, sc4.w, sh4.w), 0.f);
                yr[i] = v;
            } else {
                yr[i] = make_float4(0.f, 0.f, 0.f, 0.f);
            }
        }
        #pragma unroll
        for (int kk = 0; kk < 4; kk++) {
            float4 w4 = *(const float4*)&wlds[(kc + kk) * OUT_DIM + c0];
            #pragma unroll
            for (int i = 0; i < 4; i++) {
                float yv = ((const float*)&yr[i])[kk];
                acc[i][0] = fmaf(yv, w4.x, acc[i][0]);
                acc[i][1] = fmaf(yv, w4.y, acc[i][1]);
                acc[i][2] = fmaf(yv, w4.z, acc[i][2]);
                acc[i][3] = fmaf(yv, w4.w, acc[i][3]);
            }
        }
    }
    #pragma unroll
    for (int i = 0; i < 4; i++) {
        int r = r0 + i;
        if (r < N_NODES) {
            *(float4*)(out + (size_t)r * OUT_DIM + c0) =
                make_float4(acc[i][0], acc[i][1], acc[i][2], acc[i][3]);
        }
    }
}

// ---------------------------------------------------------------------------
// Workspace layout (4-byte elements):
//   counts    int[N]          \ zeroed together (N + 256 elements)
//   stats     float[256]      /
//   bsum      int[512]
//   row_start int[N+1]
//   next      int[N]  (padded +1 so adj stays 8B-aligned)
//   adj       int2[E]
//   x         float[N*64]
//   y1        float[N*128]
// ---------------------------------------------------------------------------
extern "C" void kernel_launch(void* const* d_in, const int* in_sizes, int n_in,
                              void* d_out, int out_size, void* d_ws, size_t ws_size,
                              hipStream_t stream)
{
    const float* feats   = (const float*)d_in[0];
    const float* edge_h  = (const float*)d_in[1];
    const int*   src     = (const int*)d_in[2];
    const int*   dst     = (const int*)d_in[3];
    const float* W1      = (const float*)d_in[4];
    const float* b1      = (const float*)d_in[5];
    const float* gamma   = (const float*)d_in[6];
    const float* bn_beta = (const float*)d_in[7];
    const float* W2      = (const float*)d_in[8];
    const float* b2      = (const float*)d_in[9];
    const float* scale   = (const float*)d_in[10];
    float* out = (float*)d_out;

    const size_t ND = (size_t)N_NODES * D_IN;
    char* ws = (char*)d_ws;
    int*   counts    = (int*)ws;                          ws += (size_t)N_NODES * 4;
    float* stats     = (float*)ws;                        ws += 256 * 4;
    int*   bsum      = (int*)ws;                          ws += 512 * 4;
    int*   row_start = (int*)ws;                          ws += (size_t)(N_NODES + 1) * 4;
    int*   next      = (int*)ws;                          ws += (size_t)(N_NODES + 1) * 4;
    int2*  adj       = (int2*)ws;                         ws += (size_t)E_EDGES * 8;
    float* xbuf      = (float*)ws;                        ws += ND * 4;
    float* y1        = (float*)ws;

    const int NB = (N_NODES + 255) / 256;   // 391

    // zero counts + stats in one memset (contiguous)
    hipMemsetAsync(counts, 0, (size_t)(N_NODES + 256) * 4, stream);

    hist_kernel<<<(E_EDGES + 255) / 256, 256, 0, stream>>>(dst, counts);
    scan1<<<NB, 256, 0, stream>>>(counts, row_start, bsum);
    scan2<<<1, 512, 0, stream>>>(bsum, NB);
    scan3<<<NB, 256, 0, stream>>>(counts, bsum, row_start, next);
    scatter_k<<<(E_EDGES + 255) / 256, 256, 0, stream>>>(dst, src, next, adj);
    aggregate<<<(N_NODES + 3) / 4, 256, 0, stream>>>(feats, edge_h, adj, row_start, scale, xbuf);
    gemm1_stats<<<(N_NODES + 31) / 32, 256, 0, stream>>>(xbuf, W1, b1, y1, stats);
    gemm2_bn<<<(N_NODES + 63) / 64, 256, 0, stream>>>(y1, W2, b2, stats, gamma, bn_beta, out);
}